// Round 16
// baseline (255.553 us; speedup 1.0000x reference)
//
#include <hip/hip_runtime.h>

#define TT 200
#define BB 256
#define DD 128
#define HH 128
#define NG 896    // 7*H semantic gate dim (gate-major: col = g*128 + u)
#define NGP 1024  // padded xg: pcol = u*8 + gate, gate 7 = zero pad

typedef _Float16 half8 __attribute__((ext_vector_type(8)));
typedef _Float16 half4 __attribute__((ext_vector_type(4)));
typedef float float4v __attribute__((ext_vector_type(4)));
typedef int int4v __attribute__((ext_vector_type(4)));

__device__ __forceinline__ float rcpf_(float x) { return __builtin_amdgcn_rcpf(x); }
__device__ __forceinline__ float sigmoidf_(float x) { return rcpf_(1.f + __expf(-x)); }
__device__ __forceinline__ float tanhf_(float x) { return 1.f - 2.f * rcpf_(__expf(2.f * x) + 1.f); }
// softplus(x) = max(x,0) + ln(1+exp(-|x|))
__device__ __forceinline__ float softplusf_(float x) {
  return fmaxf(x, 0.f) + 0.69314718056f * __log2f(1.f + __expf(-fabsf(x)));
}

#define WT_BLKS 516  // (NGP*DD + NGP)/256

// Merged prep: blocks [0,516) do WxTp/bias_p transpose; blocks [516,530) do
// W_h i8 per-column quantization (r15's parallel version).
__global__ __launch_bounds__(256) void prep_k(const float* __restrict__ Wx,
    const float* __restrict__ bias, const float* __restrict__ Wh,
    _Float16* __restrict__ WxTp, float* __restrict__ bias_p,
    char* __restrict__ WhQ, float* __restrict__ wscale) {
  int bx = blockIdx.x;
  if (bx < WT_BLKS) {
    int idx = bx * 256 + threadIdx.x;
    if (idx < NGP * DD) {
      int pcol = idx >> 7, k = idx & 127;
      int u = pcol >> 3, g = pcol & 7;
      WxTp[idx] = (g < 7) ? (_Float16)Wx[k * NG + g * HH + u] : (_Float16)0.f;
    } else if (idx < NGP * DD + NGP) {
      int pcol = idx - NGP * DD;
      int u = pcol >> 3, g = pcol & 7;
      bias_p[pcol] = (g < 7) ? bias[g * HH + u] : 0.f;
    }
    return;
  }
  // quant part
  __shared__ float redmax[4][64];
  int tid = threadIdx.x;
  int c = tid & 63, kq = tid >> 6;
  int col = (bx - WT_BLKS) * 64 + c;
  float v[32];
  float m = 0.f;
#pragma unroll
  for (int i = 0; i < 32; ++i) {
    v[i] = Wh[(size_t)(kq * 32 + i) * NG + col];
    m = fmaxf(m, fabsf(v[i]));
  }
  redmax[kq][c] = m;
  __syncthreads();
  float mm = fmaxf(fmaxf(redmax[0][c], redmax[1][c]),
                   fmaxf(redmax[2][c], redmax[3][c]));
  mm = mm > 0.f ? mm : 1.f;
  float inv = 127.f * rcpf_(mm);
  char q[32];
#pragma unroll
  for (int i = 0; i < 32; ++i) q[i] = (char)__float2int_rn(v[i] * inv);
#pragma unroll
  for (int i = 0; i < 8; ++i)
    *(int*)&WhQ[(size_t)col * DD + kq * 32 + i * 4] = *(int*)&q[i * 4];
  if (kq == 0) wscale[col] = mm * (1.f / 127.f);
}

// xg GEMM (r14 coalesced-write version) + per-row store skip: rows with
// t > rep[b] are never read by rec — don't write them (~50% write savings).
__global__ __launch_bounds__(256, 2) void xg_gemm_k(const float* __restrict__ x,
    const _Float16* __restrict__ WxTp, const float* __restrict__ bias_p,
    const int* __restrict__ rep, _Float16* __restrict__ xg, int t0) {
  int mt = blockIdx.x;
  __shared__ _Float16 Ald[128][136];
  __shared__ _Float16 Bld[128][136];
  __shared__ int tends[128];
  int tid = threadIdx.x;
  int G0 = mt * 128;
  int t = t0 + (G0 >> 8);
  int b0 = G0 & 255;
  if (tid < 128) tends[tid] = rep[b0 + tid];
  {
    int r = tid >> 5, kq = (tid & 31) << 2;
#pragma unroll
    for (int it = 0; it < 16; ++it) {
      int row = r + it * 8;
      float4v xv = *(const float4v*)(x + ((size_t)(b0 + row) * TT + t) * DD + kq);
      half4 h4 = {(_Float16)xv[0], (_Float16)xv[1], (_Float16)xv[2], (_Float16)xv[3]};
      *(half4*)&Ald[row][kq] = h4;
    }
  }
  __syncthreads();
  int wv = tid >> 6, l = tid & 63, lr = l & 15, lk8 = (l >> 4) << 3;
  half8 af[2][4];
#pragma unroll
  for (int mf = 0; mf < 2; ++mf)
#pragma unroll
    for (int kk = 0; kk < 4; ++kk)
      af[mf][kk] = *(const half8*)&Ald[wv * 32 + mf * 16 + lr][kk * 32 + lk8];
  int r4 = (l >> 4) << 2;

  for (int nt = 0; nt < 8; ++nt) {
    for (int i = tid; i < 128 * 16; i += 256) {
      int r = i >> 4, c8 = (i & 15) << 3;
      *(half8*)&Bld[r][c8] = *(const half8*)(WxTp + (size_t)(nt * 128 + r) * DD + c8);
    }
    __syncthreads();
    float4v acc[2][8];
#pragma unroll
    for (int a = 0; a < 2; ++a)
#pragma unroll
      for (int q = 0; q < 8; ++q) acc[a][q] = (float4v){0.f, 0.f, 0.f, 0.f};
#pragma unroll
    for (int kk = 0; kk < 4; ++kk) {
#pragma unroll
      for (int nf = 0; nf < 8; ++nf) {
        half8 bv = *(const half8*)&Bld[nf * 16 + lr][kk * 32 + lk8];
        acc[0][nf] = __builtin_amdgcn_mfma_f32_16x16x32_f16(af[0][kk], bv, acc[0][nf], 0, 0, 0);
        acc[1][nf] = __builtin_amdgcn_mfma_f32_16x16x32_f16(af[1][kk], bv, acc[1][nf], 0, 0, 0);
      }
    }
#pragma unroll
    for (int nf = 0; nf < 8; ++nf) {
      int colL = nf * 16 + lr;
      float bv = bias_p[nt * 128 + colL];
#pragma unroll
      for (int mf = 0; mf < 2; ++mf) {
        int rowL = wv * 32 + mf * 16 + r4;
#pragma unroll
        for (int rr = 0; rr < 4; ++rr)
          Ald[rowL + rr][colL] = (_Float16)(acc[mf][nf][rr] + bv);
      }
    }
    __syncthreads();
#pragma unroll
    for (int it = 0; it < 8; ++it) {
      int slot = tid + it * 256;
      int row = slot >> 4, cg = slot & 15;
      if (t <= tends[row]) {  // skip rows rec never reads
        half8 v = *(const half8*)&Ald[row][cg * 8];
        *(half8*)&xg[(size_t)(G0 + row) * NGP + nt * 128 + cg * 8] = v;
      }
    }
  }
}

// i8 MFMA recurrence, TWO samples per block. 1024 threads = 16 waves = 4/SIMD
// (2 per sample). The two samples' dependency chains are independent between
// barriers: sample A's VALU/trans chain overlaps sample B's MFMA cluster on
// the shared SIMD. i8 made this fit: wbq = 56 regs (vs 112 f16 in r7/r8's
// failed attempt); no prefetch regs (in-step xv load hides under the ~600 cy
// MFMA phase); gate-split accs. Target <= 128 regs/wave ((1024,4) cap).
__global__ __launch_bounds__(1024, 4) void rec_k(const _Float16* __restrict__ xg,
    const float* __restrict__ dur, const int* __restrict__ rep,
    const char* __restrict__ WhQ, const float* __restrict__ wscale,
    float* __restrict__ out,
    char* __restrict__ st_h, float* __restrict__ st_c, float* __restrict__ st_cb,
    int t0, int t1) {
  int tid = threadIdx.x;
  int s = tid >> 9, j = tid & 511;
  int b0 = blockIdx.x * 2, b = b0 + s;
  int tendA = rep[b0], tendB = rep[b0 + 1];
  int tmax = max(tendA, tendB);
  if (t0 > tmax) return;  // block-uniform
  int tend = s ? tendB : tendA;
  int tstop = min(t1 - 1, tmax);
  __shared__ __align__(16) char hq[2][2][HH];  // [buf][sample][unit]
  __shared__ float dlds[2][TT];
  int w = j >> 6, l = j & 63, lr = l & 15, lg = l >> 4;
  int u = w * 16 + lr;

  int4v wbq[7][2];
#pragma unroll
  for (int g = 0; g < 7; ++g)
#pragma unroll
    for (int m = 0; m < 2; ++m)
      wbq[g][m] = *(const int4v*)(WhQ + (size_t)(g * HH + u) * DD + m * 64 + lg * 16);
  float sg[7];
#pragma unroll
  for (int g = 0; g < 7; ++g) sg[g] = wscale[g * HH + u] * (1.f / 127.f);
  for (int i = tid; i < 2 * TT; i += 1024) {
    int ss = i / TT, ii = i - ss * TT;
    dlds[ss][ii] = dur[(b0 + ss) * TT + ii];
  }
  float c_s = 0.f, cb_s = 0.f;
  if (lg == 0) {
    hq[0][s][u] = (t0 == 0) ? (char)0 : st_h[b * HH + u];
    hq[1][s][u] = (char)0;
  }
  if (t0 != 0) {
    c_s = st_c[b * HH + u];
    cb_s = st_cb[b * HH + u];
  }
  __syncthreads();

  const _Float16* xgp = xg + (size_t)b * NGP + u * 8;
  const size_t stp = (size_t)BB * NGP;
  char hqsave = 0;

#define STEP(T, PIN, POUT)                                                       \
  do {                                                                           \
    half8 xv = *(const half8*)(xgp + (size_t)((T) - t0) * stp);                  \
    float dt = dlds[s][T];                                                       \
    int4v aq0 = *(const int4v*)&hq[PIN][s][lg * 16];                             \
    int4v aq1 = *(const int4v*)&hq[PIN][s][64 + lg * 16];                        \
    float gv[7];                                                                 \
    {                                                                            \
      int4v acc[4];                                                              \
      _Pragma("unroll") for (int g = 0; g < 4; ++g) {                            \
        acc[g] = (int4v){0, 0, 0, 0};                                            \
        acc[g] = __builtin_amdgcn_mfma_i32_16x16x64_i8(aq0, wbq[g][0], acc[g], 0, 0, 0); \
        acc[g] = __builtin_amdgcn_mfma_i32_16x16x64_i8(aq1, wbq[g][1], acc[g], 0, 0, 0); \
      }                                                                          \
      _Pragma("unroll") for (int g = 0; g < 4; ++g)                              \
          gv[g] = (float)acc[g][0] * sg[g] + (float)xv[g];                       \
    }                                                                            \
    {                                                                            \
      int4v acc[3];                                                              \
      _Pragma("unroll") for (int g = 0; g < 3; ++g) {                            \
        acc[g] = (int4v){0, 0, 0, 0};                                            \
        acc[g] = __builtin_amdgcn_mfma_i32_16x16x64_i8(aq0, wbq[g + 4][0], acc[g], 0, 0, 0); \
        acc[g] = __builtin_amdgcn_mfma_i32_16x16x64_i8(aq1, wbq[g + 4][1], acc[g], 0, 0, 0); \
      }                                                                          \
      _Pragma("unroll") for (int g = 0; g < 3; ++g)                              \
          gv[g + 4] = (float)acc[g][0] * sg[g + 4] + (float)xv[g + 4];           \
    }                                                                            \
    float iv = sigmoidf_(gv[0]), fv = sigmoidf_(gv[1]);                          \
    float zv = tanhf_(gv[2]), ov = sigmoidf_(gv[3]);                             \
    float ibv = sigmoidf_(gv[4]), fbv = sigmoidf_(gv[5]);                        \
    float dv = softplusf_(gv[6]);                                                \
    float cc = fv * c_s + iv * zv;                                               \
    cb_s = fbv * cb_s + ibv * zv;                                                \
    float cn = cb_s + (cc - cb_s) * __expf(-dv * dt);                            \
    float hn = ov * tanhf_(cn);                                                  \
    c_s = cn;                                                                    \
    char hb = (char)__float2int_rn(hn * 127.f);                                  \
    hqsave = hb;                                                                 \
    if (lg == 0) {                                                               \
      if ((T) == tend) {                                                         \
        out[b * HH + u] = hn;                                                    \
        out[BB * HH + b * HH + u] = cn;                                          \
      }                                                                          \
      hq[POUT][s][u] = hb;                                                       \
    }                                                                            \
    __syncthreads();                                                             \
  } while (0)

  for (int t = t0; t <= tstop; t += 2) {
    STEP(t, 0, 1);
    if (t + 1 <= tstop) STEP(t + 1, 1, 0);
  }
#undef STEP

  if (tstop < tend && lg == 0) {  // save state for next chunk
    st_h[b * HH + u] = hqsave;
    st_c[b * HH + u] = c_s;
    st_cb[b * HH + u] = cb_s;
  }
}

extern "C" void kernel_launch(void* const* d_in, const int* in_sizes, int n_in,
                              void* d_out, int out_size, void* d_ws, size_t ws_size,
                              hipStream_t stream) {
  const float* x = (const float*)d_in[0];
  const float* dur = (const float*)d_in[1];
  const int* rep = (const int*)d_in[2];
  const float* Wx = (const float*)d_in[3];
  const float* Wh = (const float*)d_in[4];
  const float* bias = (const float*)d_in[5];
  float* out = (float*)d_out;
  char* ws = (char*)d_ws;

  size_t off = 0;
  _Float16* WxTp = (_Float16*)(ws + off); off += (size_t)NGP * DD * 2;
  float* bias_p = (float*)(ws + off); off += (size_t)NGP * 4;
  char* WhQ = (char*)(ws + off); off += (size_t)NG * DD;
  float* wscale = (float*)(ws + off); off += (size_t)NG * 4;
  char* st_h = (char*)(ws + off); off += (size_t)BB * HH;
  float* st_c = (float*)(ws + off); off += (size_t)BB * HH * 4;
  float* st_cb = (float*)(ws + off); off += (size_t)BB * HH * 4;
  off = (off + 255) & ~(size_t)255;
  _Float16* xgbuf = (_Float16*)(ws + off);

  size_t avail = ws_size > off ? ws_size - off : 0;
  size_t perT = (size_t)BB * NGP * 2;
  int Tc = (int)(avail / perT);
  if (Tc > TT) Tc = TT;
  if (Tc < 1) Tc = 1;

  hipLaunchKernelGGL(prep_k, dim3(WT_BLKS + NG / 64), dim3(256), 0, stream,
                     Wx, bias, Wh, WxTp, bias_p, WhQ, wscale);
  for (int t0 = 0; t0 < TT; t0 += Tc) {
    int t1 = t0 + Tc;
    if (t1 > TT) t1 = TT;
    int mtiles = (t1 - t0) * BB / 128;
    hipLaunchKernelGGL(xg_gemm_k, dim3(mtiles), dim3(256), 0, stream,
                       x, WxTp, bias_p, rep, xgbuf, t0);
    hipLaunchKernelGGL(rec_k, dim3(BB / 2), dim3(1024), 0, stream,
                       xgbuf, dur, rep, WhQ, wscale, out, st_h, st_c, st_cb, t0, t1);
  }
}

// Round 17
// 154.482 us; speedup vs baseline: 1.6543x; 1.6543x over previous
//
#include <hip/hip_runtime.h>

#define TT 200
#define BB 256
#define DD 128
#define HH 128
#define NG 896    // 7*H semantic gate dim (gate-major: col = g*128 + u)
#define NGP 1024  // padded xg: pcol = u*8 + gate, gate 7 = zero pad

typedef _Float16 half8 __attribute__((ext_vector_type(8)));
typedef _Float16 half4 __attribute__((ext_vector_type(4)));
typedef float float4v __attribute__((ext_vector_type(4)));
typedef int int4v __attribute__((ext_vector_type(4)));

__device__ __forceinline__ float rcpf_(float x) { return __builtin_amdgcn_rcpf(x); }
__device__ __forceinline__ float sigmoidf_(float x) { return rcpf_(1.f + __expf(-x)); }
__device__ __forceinline__ float tanhf_(float x) { return 1.f - 2.f * rcpf_(__expf(2.f * x) + 1.f); }
// softplus(x) = max(x,0) + ln(1+exp(-|x|))
__device__ __forceinline__ float softplusf_(float x) {
  return fmaxf(x, 0.f) + 0.69314718056f * __log2f(1.f + __expf(-fabsf(x)));
}

// Merged prep, all-coalesced:
//  blocks [0,28): LDS-tiled Wx transpose (128k x 32j tile) -> WxTp[pcol][k]
//  block 28:      bias_p
//  blocks [29,43): W_h i8 per-column quantization (r15 parallel version)
__global__ __launch_bounds__(256) void prep_k(const float* __restrict__ Wx,
    const float* __restrict__ bias, const float* __restrict__ Wh,
    _Float16* __restrict__ WxTp, float* __restrict__ bias_p,
    char* __restrict__ WhQ, float* __restrict__ wscale) {
  int bx = blockIdx.x;
  int tid = threadIdx.x;
  if (bx < 28) {  // transpose tile: j in [j0, j0+32), all 128 k
    __shared__ _Float16 Tld[32][136];
    int j0 = bx * 32;
    int jo = tid & 31, kb = tid >> 5;  // 8 k-rows per iter
#pragma unroll
    for (int it = 0; it < 16; ++it) {
      int k = kb + it * 8;
      Tld[jo][k] = (_Float16)Wx[(size_t)k * NG + j0 + jo];  // coalesced over jo
    }
    __syncthreads();
    int g = j0 >> 7, u0 = j0 & 127;
    int jw = tid >> 3, kq = (tid & 7) * 16;
    int pcol = (u0 + jw) * 8 + g;
    *(half8*)&WxTp[(size_t)pcol * DD + kq] = *(const half8*)&Tld[jw][kq];
    *(half8*)&WxTp[(size_t)pcol * DD + kq + 8] = *(const half8*)&Tld[jw][kq + 8];
    return;
  }
  if (bx == 28) {  // bias_p (+ zero pad gate 7)
#pragma unroll
    for (int i = 0; i < 4; ++i) {
      int pcol = tid * 4 + i;
      int u = pcol >> 3, g = pcol & 7;
      bias_p[pcol] = (g < 7) ? bias[g * HH + u] : 0.f;
    }
    return;
  }
  // quant part: 64 cols per block
  __shared__ float redmax[4][64];
  int c = tid & 63, kq = tid >> 6;
  int col = (bx - 29) * 64 + c;
  float v[32];
  float m = 0.f;
#pragma unroll
  for (int i = 0; i < 32; ++i) {
    v[i] = Wh[(size_t)(kq * 32 + i) * NG + col];
    m = fmaxf(m, fabsf(v[i]));
  }
  redmax[kq][c] = m;
  __syncthreads();
  float mm = fmaxf(fmaxf(redmax[0][c], redmax[1][c]),
                   fmaxf(redmax[2][c], redmax[3][c]));
  mm = mm > 0.f ? mm : 1.f;
  float inv = 127.f * rcpf_(mm);
  char q[32];
#pragma unroll
  for (int i = 0; i < 32; ++i) q[i] = (char)__float2int_rn(v[i] * inv);
#pragma unroll
  for (int i = 0; i < 8; ++i)
    *(int*)&WhQ[(size_t)col * DD + kq * 32 + i * 4] = *(int*)&q[i * 4];
  if (kq == 0) wscale[col] = mm * (1.f / 127.f);
}

// xg GEMM (r14 coalesced writes + r16 skip-store of rows rec never reads)
__global__ __launch_bounds__(256, 2) void xg_gemm_k(const float* __restrict__ x,
    const _Float16* __restrict__ WxTp, const float* __restrict__ bias_p,
    const int* __restrict__ rep, _Float16* __restrict__ xg, int t0) {
  int mt = blockIdx.x;
  __shared__ _Float16 Ald[128][136];
  __shared__ _Float16 Bld[128][136];
  __shared__ int tends[128];
  int tid = threadIdx.x;
  int G0 = mt * 128;
  int t = t0 + (G0 >> 8);
  int b0 = G0 & 255;
  if (tid < 128) tends[tid] = rep[b0 + tid];
  {
    int r = tid >> 5, kq = (tid & 31) << 2;
#pragma unroll
    for (int it = 0; it < 16; ++it) {
      int row = r + it * 8;
      float4v xv = *(const float4v*)(x + ((size_t)(b0 + row) * TT + t) * DD + kq);
      half4 h4 = {(_Float16)xv[0], (_Float16)xv[1], (_Float16)xv[2], (_Float16)xv[3]};
      *(half4*)&Ald[row][kq] = h4;
    }
  }
  __syncthreads();
  int wv = tid >> 6, l = tid & 63, lr = l & 15, lk8 = (l >> 4) << 3;
  half8 af[2][4];
#pragma unroll
  for (int mf = 0; mf < 2; ++mf)
#pragma unroll
    for (int kk = 0; kk < 4; ++kk)
      af[mf][kk] = *(const half8*)&Ald[wv * 32 + mf * 16 + lr][kk * 32 + lk8];
  int r4 = (l >> 4) << 2;

  for (int nt = 0; nt < 8; ++nt) {
    for (int i = tid; i < 128 * 16; i += 256) {
      int r = i >> 4, c8 = (i & 15) << 3;
      *(half8*)&Bld[r][c8] = *(const half8*)(WxTp + (size_t)(nt * 128 + r) * DD + c8);
    }
    __syncthreads();
    float4v acc[2][8];
#pragma unroll
    for (int a = 0; a < 2; ++a)
#pragma unroll
      for (int q = 0; q < 8; ++q) acc[a][q] = (float4v){0.f, 0.f, 0.f, 0.f};
#pragma unroll
    for (int kk = 0; kk < 4; ++kk) {
#pragma unroll
      for (int nf = 0; nf < 8; ++nf) {
        half8 bv = *(const half8*)&Bld[nf * 16 + lr][kk * 32 + lk8];
        acc[0][nf] = __builtin_amdgcn_mfma_f32_16x16x32_f16(af[0][kk], bv, acc[0][nf], 0, 0, 0);
        acc[1][nf] = __builtin_amdgcn_mfma_f32_16x16x32_f16(af[1][kk], bv, acc[1][nf], 0, 0, 0);
      }
    }
#pragma unroll
    for (int nf = 0; nf < 8; ++nf) {
      int colL = nf * 16 + lr;
      float bv = bias_p[nt * 128 + colL];
#pragma unroll
      for (int mf = 0; mf < 2; ++mf) {
        int rowL = wv * 32 + mf * 16 + r4;
#pragma unroll
        for (int rr = 0; rr < 4; ++rr)
          Ald[rowL + rr][colL] = (_Float16)(acc[mf][nf][rr] + bv);
      }
    }
    __syncthreads();
#pragma unroll
    for (int it = 0; it < 8; ++it) {
      int slot = tid + it * 256;
      int row = slot >> 4, cg = slot & 15;
      if (t <= tends[row]) {  // skip rows rec never reads
        half8 v = *(const half8*)&Ald[row][cg * 8];
        *(half8*)&xg[(size_t)(G0 + row) * NGP + nt * 128 + cg * 8] = v;
      }
    }
  }
}

// MFMA recurrence, i8 weights+h — r15 champion verbatim. 1 block/sample,
// 512 threads (8 waves, 2/SIMD, 256-reg budget keeps wbq resident), one
// __syncthreads per step, 8-batch xg register prefetch.
// Structural law (r7/r8/r16): >8-wave blocks cap regs at 128/wave and break
// weight residency — do not retry TLP via bigger blocks.
__global__ __launch_bounds__(512, 2) void rec_k(const _Float16* __restrict__ xg,
    const float* __restrict__ dur, const int* __restrict__ rep,
    const char* __restrict__ WhQ, const float* __restrict__ wscale,
    float* __restrict__ out,
    char* __restrict__ st_h, float* __restrict__ st_c, float* __restrict__ st_cb,
    int t0, int t1) {
  int b = blockIdx.x, j = threadIdx.x;
  int tend = rep[b];
  if (t0 > tend) return;  // block-uniform
  int tstop = min(t1 - 1, tend);
  __shared__ __align__(16) char hq[2][HH];  // i8 h, double-buffered
  __shared__ float dlds[TT];
  int w = j >> 6, l = j & 63, lr = l & 15, lg = l >> 4;
  int u = w * 16 + lr;

  int4v wbq[7][2];
#pragma unroll
  for (int g = 0; g < 7; ++g)
#pragma unroll
    for (int m = 0; m < 2; ++m)
      wbq[g][m] = *(const int4v*)(WhQ + (size_t)(g * HH + u) * DD + m * 64 + lg * 16);
  float sg[7];
#pragma unroll
  for (int g = 0; g < 7; ++g) sg[g] = wscale[g * HH + u] * (1.f / 127.f);
  for (int i = j; i < TT; i += 512) dlds[i] = dur[b * TT + i];
  float c_s = 0.f, cb_s = 0.f;
  if (lg == 0) {
    hq[0][u] = (t0 == 0) ? (char)0 : st_h[b * HH + u];
    hq[1][u] = (char)0;
  }
  if (t0 != 0) {
    c_s = st_c[b * HH + u];
    cb_s = st_cb[b * HH + u];
  }
  __syncthreads();

  const _Float16* xgp = xg + (size_t)b * NGP + u * 8;  // + step*stp, aligned 16B
  const size_t stp = (size_t)BB * NGP;
  half8 cur[8], nxt[8];
#pragma unroll
  for (int i = 0; i < 8; ++i)
    cur[i] = *(const half8*)(xgp + (size_t)(min(t0 + i, tstop) - t0) * stp);
  char hqsave = 0;

#define STEP(T, CUR, PIN, POUT)                                                  \
  do {                                                                           \
    float dt = dlds[T];                                                          \
    int4v aq0 = *(const int4v*)&hq[PIN][lg * 16];                                \
    int4v aq1 = *(const int4v*)&hq[PIN][64 + lg * 16];                           \
    int4v acc[7];                                                                \
    _Pragma("unroll") for (int g = 0; g < 7; ++g) acc[g] = (int4v){0, 0, 0, 0};  \
    _Pragma("unroll") for (int g = 0; g < 7; ++g)                                \
        acc[g] = __builtin_amdgcn_mfma_i32_16x16x64_i8(aq0, wbq[g][0], acc[g], 0, 0, 0); \
    _Pragma("unroll") for (int g = 0; g < 7; ++g)                                \
        acc[g] = __builtin_amdgcn_mfma_i32_16x16x64_i8(aq1, wbq[g][1], acc[g], 0, 0, 0); \
    float gv[7];                                                                 \
    _Pragma("unroll") for (int g = 0; g < 7; ++g)                                \
        gv[g] = (float)acc[g][0] * sg[g] + (float)CUR[g];                        \
    float iv = sigmoidf_(gv[0]), fv = sigmoidf_(gv[1]);                          \
    float zv = tanhf_(gv[2]), ov = sigmoidf_(gv[3]);                             \
    float ibv = sigmoidf_(gv[4]), fbv = sigmoidf_(gv[5]);                        \
    float dv = softplusf_(gv[6]);                                                \
    float cc = fv * c_s + iv * zv;                                               \
    cb_s = fbv * cb_s + ibv * zv;                                                \
    float cn = cb_s + (cc - cb_s) * __expf(-dv * dt);                            \
    float hn = ov * tanhf_(cn);                                                  \
    c_s = cn;                                                                    \
    char hb = (char)__float2int_rn(hn * 127.f);                                  \
    hqsave = hb;                                                                 \
    if (lg == 0) {                                                               \
      if ((T) == tend) {                                                         \
        out[b * HH + u] = hn;                                                    \
        out[BB * HH + b * HH + u] = cn;                                          \
      }                                                                          \
      hq[POUT][u] = hb;                                                          \
    }                                                                            \
    __syncthreads();                                                             \
  } while (0)

  for (int tb = t0; tb <= tstop; tb += 8) {
#pragma unroll
    for (int i = 0; i < 8; ++i)
      nxt[i] = *(const half8*)(xgp + (size_t)(min(tb + 8 + i, tstop) - t0) * stp);
    STEP(tb, cur[0], 0, 1);
    if (tb + 1 <= tstop) STEP(tb + 1, cur[1], 1, 0);
    if (tb + 2 <= tstop) STEP(tb + 2, cur[2], 0, 1);
    if (tb + 3 <= tstop) STEP(tb + 3, cur[3], 1, 0);
    if (tb + 4 <= tstop) STEP(tb + 4, cur[4], 0, 1);
    if (tb + 5 <= tstop) STEP(tb + 5, cur[5], 1, 0);
    if (tb + 6 <= tstop) STEP(tb + 6, cur[6], 0, 1);
    if (tb + 7 <= tstop) STEP(tb + 7, cur[7], 1, 0);
#pragma unroll
    for (int i = 0; i < 8; ++i) cur[i] = nxt[i];
  }
#undef STEP

  if (tstop < tend && lg == 0) {  // save state for next chunk
    st_h[b * HH + u] = hqsave;
    st_c[b * HH + u] = c_s;
    st_cb[b * HH + u] = cb_s;
  }
}

extern "C" void kernel_launch(void* const* d_in, const int* in_sizes, int n_in,
                              void* d_out, int out_size, void* d_ws, size_t ws_size,
                              hipStream_t stream) {
  const float* x = (const float*)d_in[0];
  const float* dur = (const float*)d_in[1];
  const int* rep = (const int*)d_in[2];
  const float* Wx = (const float*)d_in[3];
  const float* Wh = (const float*)d_in[4];
  const float* bias = (const float*)d_in[5];
  float* out = (float*)d_out;
  char* ws = (char*)d_ws;

  size_t off = 0;
  _Float16* WxTp = (_Float16*)(ws + off); off += (size_t)NGP * DD * 2;
  float* bias_p = (float*)(ws + off); off += (size_t)NGP * 4;
  char* WhQ = (char*)(ws + off); off += (size_t)NG * DD;
  float* wscale = (float*)(ws + off); off += (size_t)NG * 4;
  char* st_h = (char*)(ws + off); off += (size_t)BB * HH;
  float* st_c = (float*)(ws + off); off += (size_t)BB * HH * 4;
  float* st_cb = (float*)(ws + off); off += (size_t)BB * HH * 4;
  off = (off + 255) & ~(size_t)255;
  _Float16* xgbuf = (_Float16*)(ws + off);

  size_t avail = ws_size > off ? ws_size - off : 0;
  size_t perT = (size_t)BB * NGP * 2;
  int Tc = (int)(avail / perT);
  if (Tc > TT) Tc = TT;
  if (Tc < 1) Tc = 1;

  hipLaunchKernelGGL(prep_k, dim3(29 + NG / 64), dim3(256), 0, stream,
                     Wx, bias, Wh, WxTp, bias_p, WhQ, wscale);
  for (int t0 = 0; t0 < TT; t0 += Tc) {
    int t1 = t0 + Tc;
    if (t1 > TT) t1 = TT;
    int mtiles = (t1 - t0) * BB / 128;
    hipLaunchKernelGGL(xg_gemm_k, dim3(mtiles), dim3(256), 0, stream,
                       x, WxTp, bias_p, rep, xgbuf, t0);
    hipLaunchKernelGGL(rec_k, dim3(BB), dim3(512), 0, stream,
                       xgbuf, dur, rep, WhQ, wscale, out, st_h, st_c, st_cb, t0, t1);
  }
}